// Round 8
// baseline (1267.358 us; speedup 1.0000x reference)
//
#include <hip/hip_runtime.h>

#define TT 2048
#define BQ 512
#define LAYERS 10
#define NC 7
#define CH 8               // timesteps per chunk (per barrier interval)
#define NCH (TT / CH)      // 256 chunks

// hs slot strides (dwords). Slot = [elem0: 16dw][elem1: 16dw] of f16
// z-values; dwords 13-15 / halves 25-31 are ZERO (one-time memset) so
// MFMA A-frags read k=0..31 directly.
#define E_S 16
#define C_S (2 * E_S)              // 32
#define S_S (CH * C_S)             // 256
#define P_S ((LAYERS + 1) * S_S)   // 2816

// x-part strip strides (floats): xls[w][e][j][u][g], u padded to 26
#define XU 4                       // gate quad
#define XJ (26 * XU)               // 104 (16B aligned)
#define XE (CH * XJ)               // 832
#define XW (2 * XE)                // 1664 per layer wave

typedef _Float16 half2v __attribute__((ext_vector_type(2)));
typedef _Float16 f16x8 __attribute__((ext_vector_type(8)));
typedef float f32x4 __attribute__((ext_vector_type(4)));

__device__ __forceinline__ float sigm(float z) {
  return __builtin_amdgcn_rcpf(1.0f + __expf(-z));
}
__device__ __forceinline__ float dot2(unsigned w, unsigned v, float acc) {
  return __builtin_amdgcn_fdot2(__builtin_bit_cast(half2v, w),
                                __builtin_bit_cast(half2v, v), acc, false);
}
__device__ __forceinline__ unsigned pkh2(float a, float b) {
  union { _Float16 h[2]; unsigned u; } z;
  z.h[0] = (_Float16)a; z.h[1] = (_Float16)b;
  return z.u;
}

#define LOAD13(dst, src)                             \
  do {                                               \
    *(uint4*)&(dst)[0] = *(const uint4*)((src) + 0); \
    *(uint4*)&(dst)[4] = *(const uint4*)((src) + 4); \
    *(uint4*)&(dst)[8] = *(const uint4*)((src) + 8); \
    (dst)[12] = (src)[12];                           \
  } while (0)

// R16: chunk-batched x-side + off-path redistribution. R15 post-mortem:
// MFMA pipe ~ half the step (MfmaUtil 48; 16x16x32 f16 ~19cy/SIMD; 3
// waves x 128 MFMA = 7.4K cy of an 11.2K cy step). The 8 x-side MFMAs
// per cell use 2/16 M-rows and have no recurrence dep -> batch them:
// ONE x GEMM per chunk, A rows = (j,e) (row = j+8e), 8 MFMAs/chunk.
// Redistribute ONCE per step, off the serial path (R14's mistake was
// per-cell on-path gather + 4-way scatter): scatter 32 predicated
// stores to xls[e][j][u][g], gather 8 contiguous b128/act-lane into 32
// regs. Serial loop: h-read -> 8 INDEPENDENT MFMAs (ax->ah chain gone)
// -> act (Cr_sel + xs[j][g] + bias) -> b16 publish. MFMA/wave-step
// 128 -> 72. x+h summed in f32 add (was MFMA-internal accum): ~1ulp.
__launch_bounds__(768, 3)
__global__ void lstm_fused(const float* __restrict__ x,
                           const float* __restrict__ h0,
                           const float* __restrict__ c0,
                           const float* __restrict__ Wih,
                           const float* __restrict__ Whh,
                           const float* __restrict__ bias,
                           const float* __restrict__ fcw,
                           const float* __restrict__ fcb,
                           float* __restrict__ out) {
  __shared__ __align__(16) unsigned hs[2 * P_S];
  __shared__ __align__(16) float xls[LAYERS * XW];  // x gate parts
  __shared__ float eb[2][CH][8];   // FC softmax exp staging

  const int tid = threadIdx.x;
  const int w = tid >> 6;          // 0..9 layers, 10/11 = FC+stage elem 0/1
  const int lane = tid & 63;
  const int b0 = blockIdx.x * 2;   // first batch elem of this block
  const int n15 = lane & 15;
  const int q4 = lane >> 4;
  const int arb = (n15 & 1) * E_S + 4 * q4;  // h-A-frag: elem n15&1
  const int arbx = (n15 & 7) * C_S + (n15 >> 3) * E_S + 4 * q4;  // x-A-frag
  const bool lay = (w < LAYERS);
  const int q4e = q4 & 1;                  // act: element (reg select)
  const bool q4hi = (q4 >= 2);             // act: unit-half (tile select)
  const int u = (q4hi ? 16 : 0) + n15;     // act: unit
  const bool av = lay && (!q4hi || (n15 < 9));   // 50 act-live lanes
  const bool isfc = (w >= LAYERS) && (lane < 7 * CH);
  const int efc = w - LAYERS;              // FC: which elem (0/1)
  const int jg = lane / 7;                 // FC: cell within chunk
  const int cls = lane - jg * 7;           // FC: class

  f16x8 BX[8], BH[8];              // B-frags (Wih/Whh), col-unit mapping
  unsigned Wf[13];                 // FC weights (f16 pairs)
  float bb[4] = {0.f, 0.f, 0.f, 0.f};
  float bf = 0.f;
  float c = 0.f;

  // FC-wave x staging roles: wave 10 -> elem 0, wave 11 -> elem 1.
  const int sgg = lane / 13;               // group 0..1 (lane<26)
  const int li = lane - sgg * 13;          // dword 0..12
  const int jb = sgg * 4;                  // first cell of this group
  const int i0 = 2 * li;
  const int i1 = (li < 12) ? (2 * li + 1) : 0;   // clamped in-bounds
  const bool stg = (w >= LAYERS) && (lane < 26);
  float xA[4], xB[4];
#pragma unroll
  for (int jj = 0; jj < 4; ++jj) { xA[jj] = 0.f; xB[jj] = 0.f; }

  // one-time zero of hs (pad halves must read as 0 forever)
  for (int i = tid; i < 2 * P_S; i += 768) hs[i] = 0u;

  if (lay) {
#pragma unroll
    for (int nt = 0; nt < 8; ++nt) {
      const int g = nt & 3;                // gate type i,f,g,o
      const int uu = ((nt >> 2) ? 16 : 0) + n15;     // unit of this col
      const bool gok = (uu < 25);
      const int row = 25 * g + (gok ? uu : 0);
      const float* px = Wih + (w * 100 + row) * 25;
      const float* ph = Whh + (w * 100 + row) * 25;
#pragma unroll
      for (int d = 0; d < 4; ++d) {
        const int k0 = 8 * q4 + 2 * d, k1 = k0 + 1;
        float x0 = 0.f, x1 = 0.f, h0v = 0.f, h1v = 0.f;
        if (gok && k0 < 25) { x0 = px[k0]; h0v = ph[k0]; }
        if (gok && k1 < 25) { x1 = px[k1]; h1v = ph[k1]; }
        BX[nt][2 * d]     = (_Float16)x0;
        BX[nt][2 * d + 1] = (_Float16)x1;
        BH[nt][2 * d]     = (_Float16)h0v;
        BH[nt][2 * d + 1] = (_Float16)h1v;
      }
    }
    if (av) {
#pragma unroll
      for (int g = 0; g < 4; ++g) bb[g] = bias[w * 100 + 25 * g + u];
      c = c0[(w * BQ + b0 + q4e) * 25 + u];
    }
  } else if (isfc) {
    const float* pf = fcw + cls * 25;
#pragma unroll
    for (int k = 0; k < 13; ++k) {
      const int k0 = 2 * k, k1 = 2 * k + 1;
      Wf[k] = pkh2(pf[k0], (k1 < 25) ? pf[k1] : 0.f);
    }
    bf = fcb[cls];
  }
  __syncthreads();   // zero-fill visible before staging

  // h0 -> f16 halves at [prev-parity of first active step][w+1][CH-1]
  if (av) {
    const float h00 = h0[(w * BQ + b0 + q4e) * 25 + u];
    _Float16* hp = (_Float16*)(hs + ((w & 1) ^ 1) * P_S + (w + 1) * S_S +
                               (CH - 1) * C_S);
    hp[q4e * 32 + u] = (_Float16)h00;
  }

  if (stg) {
    // chunk 0 -> parity 1 (read at m=0)
#pragma unroll
    for (int jj = 0; jj < 4; ++jj) {
      const float* p = x + ((size_t)(jb + jj) * BQ + (b0 + efc)) * 25;
      hs[1 * P_S + (jb + jj) * C_S + efc * E_S + li] =
          pkh2(p[i0], (li < 12) ? p[i1] : 0.f);
    }
    // preload chunk 1 into regs (staged to LDS at m=0)
#pragma unroll
    for (int jj = 0; jj < 4; ++jj) {
      const float* p = x + ((size_t)(CH + jb + jj) * BQ + (b0 + efc)) * 25;
      xA[jj] = p[i0];
      xB[jj] = (li < 12) ? p[i1] : 0.f;
    }
  }
  __syncthreads();

  for (int m = 0; m < NCH + LAYERS; ++m) {
    const int pr = (m & 1) ^ 1;                // read parity
    const int pw = m & 1;                      // write parity

    if (lay) {
      const int mc = m - w;                    // chunk index (wave-uniform)
      if ((unsigned)mc < (unsigned)NCH) {
        const unsigned* islot = hs + pr * P_S + w * S_S;
        const unsigned* o0p =
            hs + pr * P_S + (w + 1) * S_S + (CH - 1) * C_S + arb;
        unsigned* ob = hs + pw * P_S + (w + 1) * S_S;  // publish base
        const unsigned* obr = ob + arb;                // A-view of own h
        float* xw = xls + w * XW;

        // ---- batched x GEMM (8 MFMA/chunk) + off-path scatter
        {
          const f16x8 axc =
              __builtin_bit_cast(f16x8, *(const uint4*)(islot + arbx));
          const f32x4 z4 = {0.f, 0.f, 0.f, 0.f};
#pragma unroll
          for (int nt = 0; nt < 8; ++nt) {
            const f32x4 Cx =
                __builtin_amdgcn_mfma_f32_16x16x32_f16(axc, BX[nt], z4,
                                                       0, 0, 0);
            const int g = nt & 3;
            const int uu = ((nt >> 2) ? 16 : 0) + n15;
            if (uu < 25) {
#pragma unroll
              for (int rr = 0; rr < 4; ++rr) {
                const int row = 4 * q4 + rr;   // = j + 8e
                xw[(row >> 3) * XE + (row & 7) * XJ + uu * XU + g] = Cx[rr];
              }
            }
          }
        }
        // ---- hoisted gather: 8 contiguous b128 per act lane
        f32x4 xs[CH];
        if (av) {
#pragma unroll
          for (int j = 0; j < CH; ++j) {
            xs[j] = *(const f32x4*)(xw + q4e * XE + j * XJ + u * XU);
          }
        }

        // ---- serial h-recurrence: 8 independent MFMAs per cell
#pragma unroll
        for (int j = 0; j < CH; ++j) {
          const uint4 ahu = (j == 0) ? *(const uint4*)o0p
                                     : *(const uint4*)(obr + (j - 1) * C_S);
          const f16x8 ah = __builtin_bit_cast(f16x8, ahu);
          const f32x4 z4 = {0.f, 0.f, 0.f, 0.f};
          f32x4 Cr[8];
#pragma unroll
          for (int nt = 0; nt < 8; ++nt) {
            Cr[nt] = __builtin_amdgcn_mfma_f32_16x16x32_f16(ah, BH[nt], z4,
                                                            0, 0, 0);
          }
          if (av) {
            // static-reg quad select: tile = g + 4*q4hi, reg = q4e
            const float vi = q4hi ? (q4e ? Cr[4][1] : Cr[4][0])
                                  : (q4e ? Cr[0][1] : Cr[0][0]);
            const float vf = q4hi ? (q4e ? Cr[5][1] : Cr[5][0])
                                  : (q4e ? Cr[1][1] : Cr[1][0]);
            const float vg = q4hi ? (q4e ? Cr[6][1] : Cr[6][0])
                                  : (q4e ? Cr[2][1] : Cr[2][0]);
            const float vo = q4hi ? (q4e ? Cr[7][1] : Cr[7][0])
                                  : (q4e ? Cr[3][1] : Cr[3][0]);
            const float gi = sigm(vi + xs[j][0] + bb[0]);
            const float gf = sigm(vf + xs[j][1] + bb[1]);
            const float pg = vg + xs[j][2] + bb[2];
            const float gg = 2.0f * sigm(2.0f * pg) - 1.0f;  // tanh
            const float go = sigm(vo + xs[j][3] + bb[3]);
            c = gf * c + gi * gg;
            const float th = 2.0f * sigm(2.0f * c) - 1.0f;   // tanh(c)
            const float hv = go * th;
            _Float16* hp = (_Float16*)(ob + j * C_S);
            hp[q4e * 32 + u] = (_Float16)hv;   // one b16 publish per lane
          }
        }
      }
    } else {
      // FC waves: x staging for chunk m+1 / prefetch m+2 (stg lanes) ...
      if (stg) {
        if (m + 1 < NCH) {
#pragma unroll
          for (int jj = 0; jj < 4; ++jj) {
            hs[pw * P_S + (jb + jj) * C_S + efc * E_S + li] =
                pkh2(xA[jj], xB[jj]);
          }
        }
        if (m + 2 < NCH) {
          const size_t tb = (size_t)(m + 2) * CH + jb;
#pragma unroll
          for (int jj = 0; jj < 4; ++jj) {
            const float* p = x + ((tb + jj) * BQ + (b0 + efc)) * 25;
            xA[jj] = p[i0];
            xB[jj] = (li < 12) ? p[i1] : 0.f;
          }
        }
      }
      // ... and FC + softmax for elem efc: chunk mc = m-10 (parity pr)
      const int mc = m - LAYERS;
      if (isfc && (unsigned)mc < (unsigned)NCH) {
        const unsigned* hp =
            hs + pr * P_S + LAYERS * S_S + jg * C_S + efc * E_S;
        unsigned Hv[13];
        LOAD13(Hv, hp);
        float acc = bf;
#pragma unroll
        for (int k = 0; k < 13; ++k) acc = dot2(Wf[k], Hv[k], acc);
        const float ev = __expf(acc);           // logits small; no max-sub
        eb[efc][jg][cls] = ev;                  // same-wave LDS, ordered
        const float ssum = eb[efc][jg][0] + eb[efc][jg][1] + eb[efc][jg][2] +
                           eb[efc][jg][3] + eb[efc][jg][4] + eb[efc][jg][5] +
                           eb[efc][jg][6];
        const int t = mc * CH + jg;
        out[((size_t)t * BQ + (b0 + efc)) * NC + cls] =
            ev * __builtin_amdgcn_rcpf(ssum);
      }
    }
    __syncthreads();   // ONE barrier per chunk-step (266 total)
  }
}

extern "C" void kernel_launch(void* const* d_in, const int* in_sizes, int n_in,
                              void* d_out, int out_size, void* d_ws, size_t ws_size,
                              hipStream_t stream) {
  const float* x   = (const float*)d_in[0];
  const float* h0  = (const float*)d_in[1];
  const float* c0  = (const float*)d_in[2];
  const float* Wih = (const float*)d_in[3];
  const float* Whh = (const float*)d_in[4];
  const float* b   = (const float*)d_in[5];
  const float* fcw = (const float*)d_in[6];
  const float* fcb = (const float*)d_in[7];
  float* out = (float*)d_out;

  lstm_fused<<<dim3(256), dim3(768), 0, stream>>>(x, h0, c0, Wih, Whh, b, fcw,
                                                  fcb, out);
}